// Round 5
// baseline (190.859 us; speedup 1.0000x reference)
//
#include <hip/hip_runtime.h>
#include <math.h>

#define BLK 256
#define ESTR 56   // E/tile k-stride in elements; 112B rows: 2-way banks, 16B aligned

typedef __attribute__((ext_vector_type(8))) short s16x8;
typedef __attribute__((ext_vector_type(16))) float f32x16;

__device__ __forceinline__ float b2f(unsigned short h) {
    union { unsigned u; float f; } x; x.u = ((unsigned)h) << 16; return x.f;
}
__device__ __forceinline__ unsigned short f2b(float f) {
    union { float f; unsigned u; } x; x.f = f;
    unsigned r = x.u + 0x7fffu + ((x.u >> 16) & 1u);
    return (unsigned short)(r >> 16);
}

// MFMA 32x32x16 bf16 fragment maps (gfx950):
//   A[m][k]: m = lane&31, k = (lane>>5)*8 + j, j<8   (b128 = 8 bf16)
//   B[k][n]: n = lane&31, k = (lane>>5)*8 + j
//   C/D:     col = lane&31, row = (reg&3) + 8*(reg>>2) + 4*(lane>>5)   [m74/m101]

#define MFMA_PHASE(NKB, NNT, BT) do {                                          \
    const unsigned short* _bt = (BT);                                          \
    s16x8 _bf[NNT][NKB];                                                       \
    _Pragma("unroll") for (int nt = 0; nt < NNT; ++nt)                         \
    _Pragma("unroll") for (int kb = 0; kb < NKB; ++kb)                         \
        _bf[nt][kb] = *(const s16x8*)&_bt[(nt*4 + col)*ESTR + kb*16 + q*8];    \
    _Pragma("unroll") for (int mi = 0; mi < 4; ++mi) {                         \
        if (mi < nmt) {                                                        \
            int mt = 2*mi + half; int m0 = mt*32; if (m0 > 184) m0 = 184;      \
            s16x8 _av[NKB];                                                    \
            _Pragma("unroll") for (int kb = 0; kb < NKB; ++kb)                 \
                _av[kb] = *(const s16x8*)&Es[(m0 + col)*ESTR + kb*16 + q*8];   \
            _Pragma("unroll") for (int nt = 0; nt < NNT; ++nt)                 \
            _Pragma("unroll") for (int kb = 0; kb < NKB; ++kb)                 \
                acc[mi][nt] = __builtin_amdgcn_mfma_f32_32x32x16_bf16(         \
                    _av[kb], _bf[nt][kb], acc[mi][nt], 0, 0, 0);               \
        } } } while (0)

// PUT uses (m, n, v). Dedup: Ntile1 keeps only n>=32; Mtile6 keeps only m>=192.
#define SCATTER(NNT, NLIM, PUT) do {                                           \
    _Pragma("unroll") for (int mi = 0; mi < 4; ++mi) {                         \
      if (mi < nmt) {                                                          \
        int mt = 2*mi + half; int m0 = mt*32; if (m0 > 184) m0 = 184;          \
        _Pragma("unroll") for (int nt = 0; nt < NNT; ++nt) {                   \
            int n = nt*4 + col;                                                \
            if ((NNT == 2 && nt == 1 && n < 32) || n >= NLIM) continue;        \
            _Pragma("unroll") for (int r = 0; r < 16; ++r) {                   \
                int m = m0 + (r&3) + 8*(r>>2) + 4*q;                           \
                if (mt == 6 && m < 192) continue;                              \
                float v = acc[mi][nt][r];                                      \
                PUT;                                                           \
            } } } } } while (0)

#define ACC_ZERO() do {                                                        \
    _Pragma("unroll") for (int mi = 0; mi < 4; ++mi)                           \
    _Pragma("unroll") for (int nt = 0; nt < 2; ++nt)                           \
    _Pragma("unroll") for (int r = 0; r < 16; ++r) acc[mi][nt][r] = 0.f;       \
    } while (0)

__global__ __launch_bounds__(BLK, 2)
void peps_fwd(const float* __restrict__ inputs,
              const float* __restrict__ peps,
              const float* __restrict__ pepsc,
              float* __restrict__ out)
{
    // ~75 KB LDS -> 2 blocks/CU; grid 512 -> all co-resident.
    __shared__ __align__(16) unsigned short Ebuf[2][216 * ESTR]; // env bf16 [m][k]
    __shared__ __align__(16) unsigned short Tbuf[2][36 * ESTR];  // big tile bf16 [n][k]
    __shared__ __align__(16) float CT[2][2232]; // chain tiles 0..935, EB/T1 @936
    __shared__ float xs[64];
    __shared__ float red[104];

    const int b0  = blockIdx.x * 2;
    const int tid = threadIdx.x;
    const int lid = tid & 63;
    const int q   = lid >> 5;        // half-wave
    const int col = lid & 31;
    const int wid = tid >> 6;
    const int sw   = wid >> 1;       // slot this wave computes MFMA for
    const int half = wid & 1;        // Mtile parity
    const int nmt  = 4 - half;       // 4 or 3 Mtiles for this wave

    const unsigned short* Es = Ebuf[sw];
    unsigned short* Esw = Ebuf[sw];
    f32x16 acc[4][2];

    #define SITE(i, j) (peps + (size_t)((i) * 4 + (j)) * 2 * 1296)

    // ---- P0: zero E (incl. k-pads 36..55: A-side zeros make B k-pads inert),
    //          load x (scaled by 100: constant rescale absorbed by final norm).
    {
        unsigned* ez = (unsigned*)&Ebuf[0][0];
        for (int i = tid; i < 216 * ESTR; i += BLK) ez[i] = 0u;  // 2 slots, as uint
        if (tid < 64) xs[tid] = inputs[b0 * 32 + tid] * 100.0f;
    }
    __syncthreads();

    // ---- P1: S0 inits (bands 6 / 18, rows 0..5) + fp32 chain tiles in CT ----
    // CT per slot: T01@0 T02@216 T31@432 T32@648 T03@864 T33@900 (936), EB@936
    for (int idx = tid; idx < 216; idx += BLK) {
        int x = idx / 36, d = (idx / 6) % 6, r = idx % 6;
        const float *s01 = SITE(0,1), *s02 = SITE(0,2), *s31 = SITE(3,1), *s32 = SITE(3,2);
        int g0 = x + d * 6 + r * 36;      // row-0 tiles
        int g3 = x + d * 216 + r * 36;    // row-3 tiles
        float a, c;
        a = s01[g0]; c = s01[g0 + 1296];
        CT[0][idx]       = xs[2]  * a + xs[3]  * c;
        CT[1][idx]       = xs[34] * a + xs[35] * c;
        a = s02[g0]; c = s02[g0 + 1296];
        CT[0][216 + idx] = xs[4]  * a + xs[5]  * c;
        CT[1][216 + idx] = xs[36] * a + xs[37] * c;
        a = s31[g3]; c = s31[g3 + 1296];
        CT[0][432 + idx] = xs[26] * a + xs[27] * c;
        CT[1][432 + idx] = xs[58] * a + xs[59] * c;
        a = s32[g3]; c = s32[g3 + 1296];
        CT[0][648 + idx] = xs[28] * a + xs[29] * c;
        CT[1][648 + idx] = xs[60] * a + xs[61] * c;
    }
    for (int idx = tid; idx < 36; idx += BLK) {
        int x = idx / 6, d = idx % 6;
        const float *s03 = SITE(0,3), *s33 = SITE(3,3);
        float a, c;
        a = s03[x + d * 6];   c = s03[x + d * 6 + 1296];
        CT[0][864 + idx] = xs[6]  * a + xs[7]  * c;
        CT[1][864 + idx] = xs[38] * a + xs[39] * c;
        a = s33[x + d * 216]; c = s33[x + d * 216 + 1296];
        CT[0][900 + idx] = xs[30] * a + xs[31] * c;
        CT[1][900 + idx] = xs[62] * a + xs[63] * c;
        // S0 inits: row0 S0[d0][r0] -> band 6 ; row3 S0[u0][r0] -> band 18
        const float *s00 = SITE(0,0), *s30 = SITE(3,0);
        int u = x, r = d;
        float a0 = s00[r*36 + u*6],   c0 = s00[r*36 + u*6 + 1296];
        float a3 = s30[u*216 + r*36], c3 = s30[u*216 + r*36 + 1296];
        Ebuf[0][u*ESTR + 6  + r] = f2b(xs[0]  * a0 + xs[1]  * c0);
        Ebuf[1][u*ESTR + 6  + r] = f2b(xs[32] * a0 + xs[33] * c0);
        Ebuf[0][u*ESTR + 18 + r] = f2b(xs[24] * a3 + xs[25] * c3);
        Ebuf[1][u*ESTR + 18 + r] = f2b(xs[56] * a3 + xs[57] * c3);
    }
    __syncthreads();

    // ---- P2: chains step1 (VALU, M=6): band6 -> band12 (T01); band18 -> 24 (T31)
    for (int t2 = tid; t2 < 216; t2 += BLK) {
        int m = t2 / 36, n = t2 % 36;
        #pragma unroll
        for (int s = 0; s < 2; ++s) {
            float a0 = 0.f, a3 = 0.f;
            #pragma unroll
            for (int k = 0; k < 6; ++k) {
                a0 = fmaf(b2f(Ebuf[s][m*ESTR + 6  + k]), CT[s][k*36 + n],       a0);
                a3 = fmaf(b2f(Ebuf[s][m*ESTR + 18 + k]), CT[s][432 + k*36 + n], a3);
            }
            int o = (m*6 + n/6)*ESTR + n%6;
            Ebuf[s][o + 12] = f2b(a0);
            Ebuf[s][o + 24] = f2b(a3);
        }
    }
    __syncthreads();

    // ---- P3: chains step2 (M=36): band12 -> 6 (T02); band24 -> 18 (T32) ----
    for (int t2 = tid; t2 < 1296; t2 += BLK) {
        int m = t2 / 36, n = t2 % 36;
        #pragma unroll
        for (int s = 0; s < 2; ++s) {
            float a0 = 0.f, a3 = 0.f;
            #pragma unroll
            for (int k = 0; k < 6; ++k) {
                a0 = fmaf(b2f(Ebuf[s][m*ESTR + 12 + k]), CT[s][216 + k*36 + n], a0);
                a3 = fmaf(b2f(Ebuf[s][m*ESTR + 24 + k]), CT[s][648 + k*36 + n], a3);
            }
            int o = (m*6 + n/6)*ESTR + n%6;
            Ebuf[s][o + 6]  = f2b(a0);
            Ebuf[s][o + 18] = f2b(a3);
        }
    }
    __syncthreads();

    // ---- P4: chain tails (M=216, K=6, N=6): band6 -> E0 (cols 0..5);
    //          band18 -> EB fp32 in CT. Also build T10 (K6 tile) into Tbuf.
    for (int t2 = tid; t2 < 1296; t2 += BLK) {
        int m = t2 / 6, n = t2 % 6;
        #pragma unroll
        for (int s = 0; s < 2; ++s) {
            float a0 = 0.f, a3 = 0.f;
            #pragma unroll
            for (int k = 0; k < 6; ++k) {
                a0 = fmaf(b2f(Ebuf[s][m*ESTR + 6  + k]), CT[s][864 + k*6 + n], a0);
                a3 = fmaf(b2f(Ebuf[s][m*ESTR + 18 + k]), CT[s][900 + k*6 + n], a3);
            }
            Ebuf[s][((m % 36)*6 + n)*ESTR + m/36] = f2b(a0);       // E0 [(d1d2d3)][d0]
            CT[s][936 + (m/6)*36 + (m % 6)*6 + n] = a3;            // EB [ (d0d1) ][ (d2d3) ]
        }
    }
    {   // T10: B[k=u<6][n=(d,r)], zeros k in [6,16)
        const float* sP = SITE(1,0);
        for (int idx = tid; idx < 576; idx += BLK) {
            int n = idx / 16, k = idx % 16;
            float v0 = 0.f, v1 = 0.f;
            if (k < 6) {
                int g = k*216 + (n/6)*6 + (n%6)*36;
                float a = sP[g], c = sP[g + 1296];
                v0 = xs[8]  * a + xs[9]  * c;
                v1 = xs[40] * a + xs[41] * c;
            }
            Tbuf[0][n*ESTR + k] = f2b(v0);
            Tbuf[1][n*ESTR + k] = f2b(v1);
        }
    }
    __syncthreads();

    // helper macros for tile builds (write both slots; bf16 [n][k])
    #define BUILD_K36(SITEP, XI) do {                                          \
        const float* _s = (SITEP);                                             \
        for (int idx = tid; idx < 36*48; idx += BLK) {                         \
            int n = idx / 48, k = idx % 48;                                    \
            float v0 = 0.f, v1 = 0.f;                                          \
            if (k < 36) {                                                      \
                int g = (k/6)*216 + (k%6) + (n/6)*6 + (n%6)*36;                \
                float a = _s[g], c = _s[g + 1296];                             \
                v0 = xs[XI] * a + xs[(XI)+1] * c;                              \
                v1 = xs[32+(XI)] * a + xs[33+(XI)] * c;                        \
            }                                                                  \
            Tbuf[0][n*ESTR + k] = f2b(v0);                                     \
            Tbuf[1][n*ESTR + k] = f2b(v1);                                     \
        } } while (0)

    // ================= row 1 =================
    ACC_ZERO();
    MFMA_PHASE(1, 2, Tbuf[sw]);                       // P5: j=0 (K=6, B=T10)
    __syncthreads();
    SCATTER(2, 36, Esw[((m%36)*6 + n/6)*ESTR + (m/36)*6 + n%6] = f2b(v));  // P6
    BUILD_K36(SITE(1,1), 10);                         // T11
    __syncthreads();
    ACC_ZERO();
    MFMA_PHASE(3, 2, Tbuf[sw]);                       // P7: j=1 (K=36)
    __syncthreads();
    SCATTER(2, 36, Esw[((m%36)*6 + n/6)*ESTR + (m/36)*6 + n%6] = f2b(v));  // P8
    BUILD_K36(SITE(1,2), 12);                         // T12
    __syncthreads();
    ACC_ZERO();
    MFMA_PHASE(3, 2, Tbuf[sw]);                       // P9: j=2
    __syncthreads();
    SCATTER(2, 36, Esw[((m%36)*6 + n/6)*ESTR + (m/36)*6 + n%6] = f2b(v));  // P10
    {   // T13: B[k=(u,l)][n=d<6]: g = (k/6)*216 + (k%6) + n*6 ; k-pad 36..47 = 0
        const float* sP = SITE(1,3);
        for (int idx = tid; idx < 6*48; idx += BLK) {
            int n = idx / 48, k = idx % 48;
            float v0 = 0.f, v1 = 0.f;
            if (k < 36) {
                int g = (k/6)*216 + (k%6) + n*6;
                float a = sP[g], c = sP[g + 1296];
                v0 = xs[14] * a + xs[15] * c;
                v1 = xs[46] * a + xs[47] * c;
            }
            Tbuf[0][n*ESTR + k] = f2b(v0);
            Tbuf[1][n*ESTR + k] = f2b(v1);
        }
    }
    __syncthreads();
    ACC_ZERO();
    MFMA_PHASE(3, 1, Tbuf[sw]);                       // P11: j=3 (N=6)
    __syncthreads();
    SCATTER(1, 6, Esw[((m%36)*6 + n)*ESTR + m/36] = f2b(v));               // P12: env_top
    {   // T20 (K6 tile like T10)
        const float* sP = SITE(2,0);
        for (int idx = tid; idx < 576; idx += BLK) {
            int n = idx / 16, k = idx % 16;
            float v0 = 0.f, v1 = 0.f;
            if (k < 6) {
                int g = k*216 + (n/6)*6 + (n%6)*36;
                float a = sP[g], c = sP[g + 1296];
                v0 = xs[16] * a + xs[17] * c;
                v1 = xs[48] * a + xs[49] * c;
            }
            Tbuf[0][n*ESTR + k] = f2b(v0);
            Tbuf[1][n*ESTR + k] = f2b(v1);
        }
    }
    __syncthreads();

    // ================= row 2 =================
    ACC_ZERO();
    MFMA_PHASE(1, 2, Tbuf[sw]);                       // P13: j=0 (K=6, B=T20)
    __syncthreads();
    SCATTER(2, 36, Esw[((m%36)*6 + n/6)*ESTR + (m/36)*6 + n%6] = f2b(v));  // P14
    BUILD_K36(SITE(2,1), 18);                         // T21
    __syncthreads();
    ACC_ZERO();
    MFMA_PHASE(3, 2, Tbuf[sw]);                       // P15: j=1
    __syncthreads();
    // P16: S_pre map [(u2,u3,r1)][(d0,d1)]; convert EB fp32 -> B-tile bf16
    SCATTER(2, 36, Esw[((m/6)*6 + n%6)*ESTR + (m%6)*6 + n/6] = f2b(v));
    for (int idx = tid; idx < 36*48; idx += BLK) {
        int n = idx / 48, k = idx % 48;
        float v0 = 0.f, v1 = 0.f;
        if (k < 36) { v0 = CT[0][936 + k*36 + n]; v1 = CT[1][936 + k*36 + n]; }
        Tbuf[0][n*ESTR + k] = f2b(v0);
        Tbuf[1][n*ESTR + k] = f2b(v1);
    }
    __syncthreads();
    ACC_ZERO();
    MFMA_PHASE(3, 2, Tbuf[sw]);                       // P17: R = S_pre x EB
    __syncthreads();
    // P18: R map [(u2,r1,d2)][(u3,d3)]; build NT(2,3): B[k=(u3,d3)][n=r2<6]
    SCATTER(2, 36, Esw[((m/36)*36 + (m%6)*6 + n/6)*ESTR + ((m/6)%6)*6 + n%6] = f2b(v));
    {
        const float* sP = SITE(2,3);
        for (int idx = tid; idx < 6*48; idx += BLK) {
            int n = idx / 48, k = idx % 48;
            float v0 = 0.f, v1 = 0.f;
            if (k < 36) {
                int g = (k/6)*216 + (k%6)*6 + n;
                float a = sP[g], c = sP[g + 1296];
                v0 = xs[22] * a + xs[23] * c;
                v1 = xs[54] * a + xs[55] * c;
            }
            Tbuf[0][n*ESTR + k] = f2b(v0);
            Tbuf[1][n*ESTR + k] = f2b(v1);
        }
    }
    __syncthreads();
    ACC_ZERO();
    MFMA_PHASE(3, 1, Tbuf[sw]);                       // P19: T1 (N=6)
    SCATTER(1, 6, CT[sw][936 + m*6 + n] = v);         // T1 fp32 over dead EB
    __syncthreads();

    // ---- P20: out[o] = sum T1 * (x*C0 + x*C1), coalesced over pepsc ----
    float part[2][10];
    #pragma unroll
    for (int s = 0; s < 2; ++s)
        #pragma unroll
        for (int o = 0; o < 10; ++o) part[s][o] = 0.f;
    for (int c = tid; c < 1296; c += BLK) {
        int u2 = c / 216, r2 = (c / 36) % 6, d2 = (c / 6) % 6, r1 = c % 6;
        int e6 = u2 * 216 + r1 * 36 + d2 * 6 + r2;   // T1 flat index
        float t10 = CT[0][936 + e6], t11 = CT[1][936 + e6];
        #pragma unroll
        for (int o = 0; o < 10; ++o) {
            float c0 = pepsc[o * 1296 + c];
            float c1 = pepsc[(10 + o) * 1296 + c];
            part[0][o] = fmaf(t10, xs[20] * c0 + xs[21] * c1, part[0][o]);
            part[1][o] = fmaf(t11, xs[52] * c0 + xs[53] * c1, part[1][o]);
        }
    }
    #pragma unroll
    for (int off = 32; off >= 1; off >>= 1)
        #pragma unroll
        for (int s = 0; s < 2; ++s)
            #pragma unroll
            for (int o = 0; o < 10; ++o)
                part[s][o] += __shfl_down(part[s][o], off, 64);
    if (lid == 0) {
        #pragma unroll
        for (int s = 0; s < 2; ++s)
            #pragma unroll
            for (int o = 0; o < 10; ++o)
                red[s * 52 + wid * 10 + o] = part[s][o];
    }
    __syncthreads();
    {
        int s = tid >> 7, t = tid & 127;
        if (t < 10)
            red[s * 52 + 40 + t] = red[s * 52 + t] + red[s * 52 + 10 + t]
                                 + red[s * 52 + 20 + t] + red[s * 52 + 30 + t];
        __syncthreads();
        if (t == 0) {
            float n2 = 0.f;
            #pragma unroll
            for (int o = 0; o < 10; ++o) n2 += red[s * 52 + 40 + o] * red[s * 52 + 40 + o];
            red[s * 52 + 50] = 1.0f / sqrtf(n2);
        }
        __syncthreads();
        if (t < 10) out[(b0 + s) * 10 + t] = red[s * 52 + 40 + t] * red[s * 52 + 50];
    }
    #undef SITE
    #undef BUILD_K36
}

extern "C" void kernel_launch(void* const* d_in, const int* in_sizes, int n_in,
                              void* d_out, int out_size, void* d_ws, size_t ws_size,
                              hipStream_t stream) {
    const float* inputs = (const float*)d_in[0];   // (B,4,4,2) f32
    const float* peps   = (const float*)d_in[1];   // (4,4,2,6,6,6,6) f32
    const float* pepsc  = (const float*)d_in[2];   // (2,10,6,6,6,6) f32
    float* outp = (float*)d_out;                   // (B,10) f32
    const int B = in_sizes[0] / 32;
    peps_fwd<<<dim3(B / 2), dim3(BLK), 0, stream>>>(inputs, peps, pepsc, outp);
}

// Round 6
// 116.246 us; speedup vs baseline: 1.6419x; 1.6419x over previous
//
#include <hip/hip_runtime.h>
#include <math.h>

#define BLK 256
#define ESTR 56   // E/tile k-stride (shorts); 112B rows, 16B-aligned frags

typedef __attribute__((ext_vector_type(8))) short s16x8;
typedef __attribute__((ext_vector_type(16))) float f32x16;

__device__ __forceinline__ float b2f(unsigned short h) {
    union { unsigned u; float f; } x; x.u = ((unsigned)h) << 16; return x.f;
}
__device__ __forceinline__ unsigned short f2b(float f) {
    union { float f; unsigned u; } x; x.f = f;
    unsigned r = x.u + 0x7fffu + ((x.u >> 16) & 1u);
    return (unsigned short)(r >> 16);
}

// MFMA 32x32x16 bf16 (gfx950):
//   A[m][k]: m = lane&31, k = (lane>>5)*8 + j   (s16x8 = one b128)
//   B[k][n]: n = lane&31, same k
//   C/D:     col = lane&31, row = (reg&3) + 8*(reg>>2) + 4*(lane>>5)  [m74/m101]
// Wave w owns Mtiles {w, w+4} (w<3) / {3} (w==3). Mtile6 covers m 184..215
// (dedup: keep m>=192). Ntile1 covers n 4..35 (dedup: keep n>=32).

#define MFMA_PHASE(NKB, NNT) do {                                              \
    s16x8 _bf[NNT][NKB];                                                       \
    _Pragma("unroll") for (int nt = 0; nt < NNT; ++nt)                         \
    _Pragma("unroll") for (int kb = 0; kb < NKB; ++kb)                         \
        _bf[nt][kb] = *(const s16x8*)&Tbuf[(nt*4 + col)*ESTR + kb*16 + q*8];   \
    _Pragma("unroll") for (int i = 0; i < 2; ++i) {                            \
        if (i < nmt) {                                                         \
            int mt = wid + 4*i; int m0 = (mt == 6) ? 184 : mt*32;              \
            s16x8 _av[NKB];                                                    \
            _Pragma("unroll") for (int kb = 0; kb < NKB; ++kb)                 \
                _av[kb] = *(const s16x8*)&Ebuf[(m0 + col)*ESTR + kb*16 + q*8]; \
            _Pragma("unroll") for (int nt = 0; nt < NNT; ++nt)                 \
            _Pragma("unroll") for (int kb = 0; kb < NKB; ++kb)                 \
                acc[i][nt] = __builtin_amdgcn_mfma_f32_32x32x16_bf16(          \
                    _av[kb], _bf[nt][kb], acc[i][nt], 0, 0, 0);                \
        } } } while (0)

#define SCATTER(NNT, NLIM, PUT) do {                                           \
    _Pragma("unroll") for (int i = 0; i < 2; ++i) {                            \
      if (i < nmt) {                                                           \
        int mt = wid + 4*i; int m0 = (mt == 6) ? 184 : mt*32;                  \
        _Pragma("unroll") for (int nt = 0; nt < NNT; ++nt) {                   \
            int n = nt*4 + col;                                                \
            if ((NNT == 2 && nt == 1 && n < 32) || n >= NLIM) continue;        \
            _Pragma("unroll") for (int r = 0; r < 16; ++r) {                   \
                int m = m0 + (r&3) + 8*(r>>2) + 4*q;                           \
                if (mt == 6 && m < 192) continue;                              \
                float v = acc[i][nt][r];                                       \
                PUT;                                                           \
            } } } } } while (0)

#define ACC_ZERO() do {                                                        \
    _Pragma("unroll") for (int i = 0; i < 2; ++i)                              \
    _Pragma("unroll") for (int nt = 0; nt < 2; ++nt)                           \
    _Pragma("unroll") for (int r = 0; r < 16; ++r) acc[i][nt][r] = 0.f;        \
    } while (0)

__global__ __launch_bounds__(BLK, 3)
void peps_fwd(const float* __restrict__ inputs,
              const float* __restrict__ peps,
              const float* __restrict__ pepsc,
              float* __restrict__ out)
{
    // ~37.6 KB LDS; launch_bounds(256,3) -> 3 blocks/CU (VGPR<=170).
    __shared__ __align__(16) unsigned short Ebuf[216 * ESTR]; // env bf16 [m][k]
    __shared__ __align__(16) unsigned short Tbuf[36 * ESTR];  // B tile bf16 [n][k]
    __shared__ __align__(16) float CT[2232];  // chain tiles 0..935; EB/T1 @936
    __shared__ float xs[32];
    __shared__ float red[52];

    const int b   = blockIdx.x;
    const int tid = threadIdx.x;
    const int lid = tid & 63;
    const int q   = lid >> 5;
    const int col = lid & 31;
    const int wid = tid >> 6;
    const int nmt = (wid < 3) ? 2 : 1;

    f32x16 acc[2][2];

    #define SITE(i, j) (peps + (size_t)((i) * 4 + (j)) * 2 * 1296)

    // ---- P0: zero E (k-pads 36..55 stay 0 forever -> inert in MFMA);
    //          x scaled by 100 (constant rescale, absorbed by final norm).
    {
        unsigned* ez = (unsigned*)&Ebuf[0];
        for (int i = tid; i < 108 * ESTR; i += BLK) ez[i] = 0u;
        if (tid < 32) xs[tid] = inputs[b * 32 + tid] * 100.0f;
    }
    __syncthreads();

    // ---- P1: fp32 chain tiles in CT + S0 inits (bands 6 / 18) -------------
    // CT: T01@0 T02@216 T31@432 T32@648 T03@864 T33@900 (936); EB@936
    for (int idx = tid; idx < 216; idx += BLK) {
        int x = idx / 36, d = (idx / 6) % 6, r = idx % 6;
        const float *s01 = SITE(0,1), *s02 = SITE(0,2), *s31 = SITE(3,1), *s32 = SITE(3,2);
        int g0 = x + d * 6 + r * 36;      // row-0 tiles
        int g3 = x + d * 216 + r * 36;    // row-3 tiles
        CT[idx]       = xs[2]  * s01[g0] + xs[3]  * s01[g0 + 1296];
        CT[216 + idx] = xs[4]  * s02[g0] + xs[5]  * s02[g0 + 1296];
        CT[432 + idx] = xs[26] * s31[g3] + xs[27] * s31[g3 + 1296];
        CT[648 + idx] = xs[28] * s32[g3] + xs[29] * s32[g3 + 1296];
    }
    for (int idx = tid; idx < 36; idx += BLK) {
        int x = idx / 6, d = idx % 6;
        const float *s03 = SITE(0,3), *s33 = SITE(3,3);
        CT[864 + idx] = xs[6]  * s03[x + d*6]   + xs[7]  * s03[x + d*6 + 1296];
        CT[900 + idx] = xs[30] * s33[x + d*216] + xs[31] * s33[x + d*216 + 1296];
        const float *s00 = SITE(0,0), *s30 = SITE(3,0);
        int u = x, r = d;
        // row0 S0[d0][r0] -> band 6 ; row3 S0[u0][r0] -> band 18
        Ebuf[u*ESTR + 6  + r] = f2b(xs[0]  * s00[r*36 + u*6]   + xs[1]  * s00[r*36 + u*6 + 1296]);
        Ebuf[u*ESTR + 18 + r] = f2b(xs[24] * s30[u*216 + r*36] + xs[25] * s30[u*216 + r*36 + 1296]);
    }
    __syncthreads();

    // ---- P2: chains step1 (M=6): band6->12 (T01); band18->24 (T31) --------
    for (int t2 = tid; t2 < 216; t2 += BLK) {
        int m = t2 / 36, n = t2 % 36;
        float a0 = 0.f, a3 = 0.f;
        #pragma unroll
        for (int k = 0; k < 6; ++k) {
            a0 = fmaf(b2f(Ebuf[m*ESTR + 6  + k]), CT[k*36 + n],       a0);
            a3 = fmaf(b2f(Ebuf[m*ESTR + 18 + k]), CT[432 + k*36 + n], a3);
        }
        int o = (m*6 + n/6)*ESTR + n%6;
        Ebuf[o + 12] = f2b(a0);
        Ebuf[o + 24] = f2b(a3);
    }
    __syncthreads();

    // ---- P3: chains step2 (M=36): band12->6 (T02); band24->18 (T32) -------
    for (int t2 = tid; t2 < 1296; t2 += BLK) {
        int m = t2 / 36, n = t2 % 36;
        float a0 = 0.f, a3 = 0.f;
        #pragma unroll
        for (int k = 0; k < 6; ++k) {
            a0 = fmaf(b2f(Ebuf[m*ESTR + 12 + k]), CT[216 + k*36 + n], a0);
            a3 = fmaf(b2f(Ebuf[m*ESTR + 24 + k]), CT[648 + k*36 + n], a3);
        }
        int o = (m*6 + n/6)*ESTR + n%6;
        Ebuf[o + 6]  = f2b(a0);
        Ebuf[o + 18] = f2b(a3);
    }
    __syncthreads();

    // ---- P4: tails (M=216,K=6,N=6): band6 -> E0 (cols 0..5); band18 -> EB fp32.
    //          Also build T10 (K6 B-tile, k-pad [6,16) zeroed).
    for (int t2 = tid; t2 < 1296; t2 += BLK) {
        int m = t2 / 6, n = t2 % 6;
        float a0 = 0.f, a3 = 0.f;
        #pragma unroll
        for (int k = 0; k < 6; ++k) {
            a0 = fmaf(b2f(Ebuf[m*ESTR + 6  + k]), CT[864 + k*6 + n], a0);
            a3 = fmaf(b2f(Ebuf[m*ESTR + 18 + k]), CT[900 + k*6 + n], a3);
        }
        Ebuf[((m % 36)*6 + n)*ESTR + m/36] = f2b(a0);     // E0 [(d1d2d3)][d0]
        CT[936 + (m/6)*36 + (m % 6)*6 + n] = a3;          // EB [(d0d1)][(d2d3)]
    }
    {
        const float* sP = SITE(1,0);
        for (int idx = tid; idx < 576; idx += BLK) {
            int n = idx / 16, k = idx % 16;
            float v = 0.f;
            if (k < 6) {
                int g = k*216 + (n/6)*6 + (n%6)*36;
                v = xs[8] * sP[g] + xs[9] * sP[g + 1296];
            }
            Tbuf[n*ESTR + k] = f2b(v);
        }
    }
    __syncthreads();

    #define BUILD_K36(SITEP, XI) do {                                          \
        const float* _s = (SITEP);                                             \
        for (int idx = tid; idx < 36*48; idx += BLK) {                         \
            int n = idx / 48, k = idx % 48;                                    \
            float v = 0.f;                                                     \
            if (k < 36) {                                                      \
                int g = (k/6)*216 + (k%6) + (n/6)*6 + (n%6)*36;                \
                v = xs[XI] * _s[g] + xs[(XI)+1] * _s[g + 1296];                \
            }                                                                  \
            Tbuf[n*ESTR + k] = f2b(v);                                         \
        } } while (0)

    #define BUILD_N6(SITEP, XI, GEXPR) do {                                    \
        const float* _s = (SITEP);                                             \
        for (int idx = tid; idx < 6*48; idx += BLK) {                          \
            int n = idx / 48, k = idx % 48;                                    \
            float v = 0.f;                                                     \
            if (k < 36) {                                                      \
                int g = (GEXPR);                                               \
                v = xs[XI] * _s[g] + xs[(XI)+1] * _s[g + 1296];                \
            }                                                                  \
            Tbuf[n*ESTR + k] = f2b(v);                                         \
        } } while (0)

    #define BUILD_K6(SITEP, XI) do {                                           \
        const float* _s = (SITEP);                                             \
        for (int idx = tid; idx < 576; idx += BLK) {                           \
            int n = idx / 16, k = idx % 16;                                    \
            float v = 0.f;                                                     \
            if (k < 6) {                                                       \
                int g = k*216 + (n/6)*6 + (n%6)*36;                            \
                v = xs[XI] * _s[g] + xs[(XI)+1] * _s[g + 1296];                \
            }                                                                  \
            Tbuf[n*ESTR + k] = f2b(v);                                         \
        } } while (0)

    // ================= row 1 =================
    ACC_ZERO();
    MFMA_PHASE(1, 2);                                 // P5: j=0 (K=6, T10)
    __syncthreads();
    SCATTER(2, 36, Ebuf[((m%36)*6 + n/6)*ESTR + (m/36)*6 + n%6] = f2b(v));  // P6
    BUILD_K36(SITE(1,1), 10);
    __syncthreads();
    ACC_ZERO();
    MFMA_PHASE(3, 2);                                 // P7: j=1 (K=36)
    __syncthreads();
    SCATTER(2, 36, Ebuf[((m%36)*6 + n/6)*ESTR + (m/36)*6 + n%6] = f2b(v));  // P8
    BUILD_K36(SITE(1,2), 12);
    __syncthreads();
    ACC_ZERO();
    MFMA_PHASE(3, 2);                                 // P9: j=2
    __syncthreads();
    SCATTER(2, 36, Ebuf[((m%36)*6 + n/6)*ESTR + (m/36)*6 + n%6] = f2b(v));  // P10
    BUILD_N6(SITE(1,3), 14, (k/6)*216 + (k%6) + n*6); // T13 [k=(u,l)][n=d]
    __syncthreads();
    ACC_ZERO();
    MFMA_PHASE(3, 1);                                 // P11: j=3 (N=6)
    __syncthreads();
    SCATTER(1, 6, Ebuf[((m%36)*6 + n)*ESTR + m/36] = f2b(v));  // P12: env_top
    BUILD_K6(SITE(2,0), 16);                          // T20
    __syncthreads();

    // ================= row 2 =================
    ACC_ZERO();
    MFMA_PHASE(1, 2);                                 // P13: j=0 (K=6, T20)
    __syncthreads();
    SCATTER(2, 36, Ebuf[((m%36)*6 + n/6)*ESTR + (m/36)*6 + n%6] = f2b(v));  // P14
    BUILD_K36(SITE(2,1), 18);
    __syncthreads();
    ACC_ZERO();
    MFMA_PHASE(3, 2);                                 // P15: j=1
    __syncthreads();
    // P16: S_pre map [(u2,u3,r1)][(d0,d1)]; EB fp32 -> B tile bf16
    SCATTER(2, 36, Ebuf[((m/6)*6 + n%6)*ESTR + (m%6)*6 + n/6] = f2b(v));
    for (int idx = tid; idx < 36*48; idx += BLK) {
        int n = idx / 48, k = idx % 48;
        float v = (k < 36) ? CT[936 + k*36 + n] : 0.f;
        Tbuf[n*ESTR + k] = f2b(v);
    }
    __syncthreads();
    ACC_ZERO();
    MFMA_PHASE(3, 2);                                 // P17: R = S_pre x EB
    __syncthreads();
    // P18: R map [(u2,r1,d2)][(u3,d3)]; build NT(2,3) [k=(u3,d3)][n=r2]
    SCATTER(2, 36, Ebuf[((m/36)*36 + (m%6)*6 + n/6)*ESTR + ((m/6)%6)*6 + n%6] = f2b(v));
    BUILD_N6(SITE(2,3), 22, (k/6)*216 + (k%6)*6 + n);
    __syncthreads();
    ACC_ZERO();
    MFMA_PHASE(3, 1);                                 // P19: T1 (N=6)
    SCATTER(1, 6, CT[936 + m*6 + n] = v);             // T1 fp32 over dead EB
    __syncthreads();

    // ---- P20: out[o] = sum T1 * (x20*C0 + x21*C1), coalesced over pepsc ----
    float part[10];
    #pragma unroll
    for (int o = 0; o < 10; ++o) part[o] = 0.f;
    for (int c = tid; c < 1296; c += BLK) {
        int u2 = c / 216, r2 = (c / 36) % 6, d2 = (c / 6) % 6, r1 = c % 6;
        float t1 = CT[936 + u2*216 + r1*36 + d2*6 + r2];
        #pragma unroll
        for (int o = 0; o < 10; ++o) {
            float c0 = pepsc[o * 1296 + c];
            float c1 = pepsc[(10 + o) * 1296 + c];
            part[o] = fmaf(t1, xs[20] * c0 + xs[21] * c1, part[o]);
        }
    }
    #pragma unroll
    for (int off = 32; off >= 1; off >>= 1)
        #pragma unroll
        for (int o = 0; o < 10; ++o)
            part[o] += __shfl_down(part[o], off, 64);
    if (lid == 0) {
        #pragma unroll
        for (int o = 0; o < 10; ++o) red[wid * 10 + o] = part[o];
    }
    __syncthreads();
    if (tid < 10)
        red[40 + tid] = red[tid] + red[10 + tid] + red[20 + tid] + red[30 + tid];
    __syncthreads();
    if (tid == 0) {
        float n2 = 0.f;
        #pragma unroll
        for (int o = 0; o < 10; ++o) n2 += red[40 + o] * red[40 + o];
        red[50] = 1.0f / sqrtf(n2);
    }
    __syncthreads();
    if (tid < 10) out[b * 10 + tid] = red[40 + tid] * red[50];
    #undef SITE
    #undef BUILD_K36
    #undef BUILD_N6
    #undef BUILD_K6
}

extern "C" void kernel_launch(void* const* d_in, const int* in_sizes, int n_in,
                              void* d_out, int out_size, void* d_ws, size_t ws_size,
                              hipStream_t stream) {
    const float* inputs = (const float*)d_in[0];   // (B,4,4,2) f32
    const float* peps   = (const float*)d_in[1];   // (4,4,2,6,6,6,6) f32
    const float* pepsc  = (const float*)d_in[2];   // (2,10,6,6,6,6) f32
    float* outp = (float*)d_out;                   // (B,10) f32
    const int B = in_sizes[0] / 32;
    peps_fwd<<<dim3(B), dim3(BLK), 0, stream>>>(inputs, peps, pepsc, outp);
}